// Round 10
// baseline (105.858 us; speedup 1.0000x reference)
//
#include <hip/hip_runtime.h>
#include <hip/hip_bf16.h>
#include <math.h>

// GConvLSTM cell via MFMA (graph inputs are dead code in the reference).
// Transposed gate GEMM (R7 layout): g^T = W^T @ [x|h|1]^T via
// mfma_f32_16x16x32_bf16(A=W-frag, B=X-frag); lane (q=lane&15, kb=lane>>4)
// owns node gb0+q, dims kb*4..kb*4+3 of every gate -> all c/h_new/c_new
// accesses are wave-contiguous float4; out-reduce = in-lane 4-dot + 2 shfl.
// R10 vs R9: BIAS THROUGH THE MFMA — W row 24 = bx+bh+b_gates (bf16), kb==3
// lanes' X-frag = {1,0,...} constant (they multiplied zero rows before).
// Frees all 16 bias VGPRs -> 64-VGPR target -> 8 blocks/CU capacity -> whole
// 1953-block grid resident in ONE round (was 1.27 rounds at 76 VGPR: ~27%
// ragged tail, the R9 bottleneck). __launch_bounds__(256,8) pins the cap.
// Keeps: 2-deep pipeline (R9), nontemporal h_new/c_new stores (R8).
// d_out layout: [N] out | [N*16] h_new | [N*16] c_new.  Requires n % 16 == 0.

typedef short bf16x8 __attribute__((ext_vector_type(8)));
typedef float f32x4 __attribute__((ext_vector_type(4)));

#define LOG2E 1.44269504088896f

__device__ __forceinline__ float sig1(float v) {
    return __builtin_amdgcn_rcpf(1.0f + __builtin_amdgcn_exp2f(-LOG2E * v));
}
__device__ __forceinline__ float tanh1(float v) {
    return 1.0f - 2.0f * __builtin_amdgcn_rcpf(__builtin_amdgcn_exp2f((2.0f * LOG2E) * v) + 1.0f);
}
__device__ __forceinline__ f32x4 sig4(f32x4 v) {
    f32x4 r; r[0]=sig1(v[0]); r[1]=sig1(v[1]); r[2]=sig1(v[2]); r[3]=sig1(v[3]); return r;
}
__device__ __forceinline__ f32x4 tanh4(f32x4 v) {
    f32x4 r; r[0]=tanh1(v[0]); r[1]=tanh1(v[1]); r[2]=tanh1(v[2]); r[3]=tanh1(v[3]); return r;
}
__device__ __forceinline__ short f2bf(float f) {
    __bf16 b = (__bf16)f;          // pairs fuse to v_cvt_pk_bf16_f32
    short s; __builtin_memcpy(&s, &b, 2); return s;
}
__device__ __forceinline__ f32x4 max4z(f32x4 a) {
    f32x4 r; r[0]=fmaxf(a[0],0.f); r[1]=fmaxf(a[1],0.f); r[2]=fmaxf(a[2],0.f); r[3]=fmaxf(a[3],0.f); return r;
}

#define IW 8                       // 64-node tiles per block (even!)
#define NPB (64 * IW)              // 512 nodes per block

__global__ __launch_bounds__(256, 8) void lstm_mfma_kernel(
    const float* __restrict__ x,       // N x 8
    const float* __restrict__ h,       // N x 16
    const float* __restrict__ c,       // N x 16
    const float* __restrict__ Wx,      // 8 x 64
    const float* __restrict__ bx,      // 64
    const float* __restrict__ Wh,      // 16 x 64
    const float* __restrict__ bh,      // 64
    const float* __restrict__ w_peep,  // 3 x 16
    const float* __restrict__ b_gates, // 4 x 16
    const float* __restrict__ W_lin,   // 16
    const float* __restrict__ b_lin,   // 1
    float* __restrict__ dout,
    int n)
{
    const int lane = threadIdx.x & 63;
    const int wave = threadIdx.x >> 6;
    const int q  = lane & 15;   // A-role: dim; B/D-role: node offset
    const int kb = lane >> 4;   // k-block (8 k's each); D-role: dim block
    const bool kb3 = (kb == 3);

    // ---- weight A-fragment: wfrag[t][e] = W[kb*8+e][t*16+q]
    // W = [Wx(8) ; Wh(16) ; bias-row(1) ; 0pad(7)], bias row = bx+bh+b_gates.
    // kb==3 X-frag is the constant {1,0,...}: bias*1 lands in the accumulator,
    // rows 25..31 are zero.
    bf16x8 wfrag[4];
    #pragma unroll
    for (int t = 0; t < 4; ++t) {
        #pragma unroll
        for (int e = 0; e < 8; ++e) {
            const int r = kb * 8 + e;
            float w = 0.0f;
            if (r < 8)        w = Wx[r * 64 + t * 16 + q];
            else if (r < 24)  w = Wh[(r - 8) * 64 + t * 16 + q];
            else if (r == 24) w = bx[t * 16 + q] + bh[t * 16 + q] + b_gates[t * 16 + q];
            wfrag[t][e] = f2bf(w);
        }
    }

    // ---- per-lane epilogue constants for dims dd..dd+3
    const int dd = kb * 4;
    f32x4 pp0, pp1, pp2, wl4;
    #pragma unroll
    for (int e = 0; e < 4; ++e) {
        pp0[e] = w_peep[dd + e]; pp1[e] = w_peep[16 + dd + e]; pp2[e] = w_peep[32 + dd + e];
        wl4[e] = W_lin[dd + e];
    }
    const float bl = b_lin[0];

    const unsigned blockBase = (unsigned)blockIdx.x * NPB;
    const unsigned gb0   = blockBase + (unsigned)wave * 16u;  // wave's first node
    const unsigned node0 = gb0 + (unsigned)q;

    // per-lane X pointer (B-frag): x rows for kb==0, h rows otherwise
    // (kb==3 loads are discarded: xf is overwritten with {1,0,...})
    const float* aptr;
    unsigned astride;
    if (kb == 0) { aptr = x + (size_t)node0 * 8;                        astride = 64u * 8;  }
    else         { aptr = h + (size_t)node0 * 16 + ((kb == 2) ? 8 : 0); astride = 64u * 16; }

    const unsigned co0 = node0 * 16u + (unsigned)dd;  // c / h_new / c_new float4 offset
    const unsigned ro0 = node0;                       // out offset (kb==0 lanes store)
    float* hob = dout + (size_t)n;        // h_new base
    float* cob = dout + (size_t)n * 17;   // c_new base

    // compute one iteration from registers A0,A1,CV; stores at CO/RO
#define COMPUTE(A0, A1, CV, CO, RO)                                            \
    {                                                                          \
        bf16x8 xf;                                                             \
        xf[0] = f2bf((A0).x); xf[1] = f2bf((A0).y);                            \
        xf[2] = f2bf((A0).z); xf[3] = f2bf((A0).w);                            \
        xf[4] = f2bf((A1).x); xf[5] = f2bf((A1).y);                            \
        xf[6] = f2bf((A1).z); xf[7] = f2bf((A1).w);                            \
        if (kb3) {                                                             \
            xf[0] = (short)0x3F80; xf[1] = 0; xf[2] = 0; xf[3] = 0;            \
            xf[4] = 0; xf[5] = 0; xf[6] = 0; xf[7] = 0;                        \
        }                                                                      \
        f32x4 accI = {0.f, 0.f, 0.f, 0.f};                                     \
        f32x4 accF = {0.f, 0.f, 0.f, 0.f};                                     \
        f32x4 accC = {0.f, 0.f, 0.f, 0.f};                                     \
        f32x4 accO = {0.f, 0.f, 0.f, 0.f};                                     \
        accI = __builtin_amdgcn_mfma_f32_16x16x32_bf16(wfrag[0], xf, accI, 0, 0, 0); \
        accF = __builtin_amdgcn_mfma_f32_16x16x32_bf16(wfrag[1], xf, accF, 0, 0, 0); \
        accC = __builtin_amdgcn_mfma_f32_16x16x32_bf16(wfrag[2], xf, accC, 0, 0, 0); \
        accO = __builtin_amdgcn_mfma_f32_16x16x32_bf16(wfrag[3], xf, accO, 0, 0, 0); \
        f32x4 iv = sig4(pp0 * (CV) + accI);                                    \
        f32x4 fv = sig4(pp1 * (CV) + accF);                                    \
        f32x4 tv = tanh4(accC);                                                \
        f32x4 cn = fv * (CV) + iv * tv;                                        \
        f32x4 ov = sig4(pp2 * cn + accO);                                      \
        f32x4 hn = ov * tanh4(cn);                                             \
        __builtin_nontemporal_store(hn, reinterpret_cast<f32x4*>(hob + (CO))); \
        __builtin_nontemporal_store(cn, reinterpret_cast<f32x4*>(cob + (CO))); \
        f32x4 rr = max4z(hn) * wl4;                                            \
        float os = (rr[0] + rr[1]) + (rr[2] + rr[3]);                          \
        os += __shfl_xor(os, 16);                                              \
        os += __shfl_xor(os, 32);                                              \
        if (kb == 0) dout[RO] = os + bl;                                       \
    }

    if (blockBase + NPB <= (unsigned)n) {
        // full block: 2-deep pipeline with two named register sets.
        // A = even iterations (0,2,4,6), B = odd iterations (1,3,5,7).
        const float* apA = aptr;
        const float* apB = aptr + astride;
        unsigned coA = co0,        coB = co0 + 1024u;
        unsigned roA = ro0,        roB = ro0 + 64u;
        const unsigned astep = 2u * astride;

        float4 a0A = *reinterpret_cast<const float4*>(apA);
        float4 a1A = *reinterpret_cast<const float4*>(apA + 4);
        f32x4  cvA = *reinterpret_cast<const f32x4*>(c + coA);
        float4 a0B = *reinterpret_cast<const float4*>(apB);
        float4 a1B = *reinterpret_cast<const float4*>(apB + 4);
        f32x4  cvB = *reinterpret_cast<const f32x4*>(c + coB);

        #pragma unroll 1
        for (int k = 0; k < (IW - 2) / 2; ++k) {
            // prefetch iter 2k+2 (next A), then compute iter 2k (A)
            const float* npA = apA + astep;
            float4 t0 = *reinterpret_cast<const float4*>(npA);
            float4 t1 = *reinterpret_cast<const float4*>(npA + 4);
            f32x4  tc = *reinterpret_cast<const f32x4*>(c + coA + 2048u);
            COMPUTE(a0A, a1A, cvA, coA, roA);
            a0A = t0; a1A = t1; cvA = tc;
            apA = npA; coA += 2048u; roA += 128u;

            // prefetch iter 2k+3 (next B), then compute iter 2k+1 (B)
            const float* npB = apB + astep;
            float4 u0 = *reinterpret_cast<const float4*>(npB);
            float4 u1 = *reinterpret_cast<const float4*>(npB + 4);
            f32x4  uc = *reinterpret_cast<const f32x4*>(c + coB + 2048u);
            COMPUTE(a0B, a1B, cvB, coB, roB);
            a0B = u0; a1B = u1; cvB = uc;
            apB = npB; coB += 2048u; roB += 128u;
        }
        COMPUTE(a0A, a1A, cvA, coA, roA);   // iter IW-2
        COMPUTE(a0B, a1B, cvB, coB, roB);   // iter IW-1
    } else {
        // tail block (at most one): group-granular bounds check (n % 16 == 0)
        const float* ap = aptr;
        unsigned co = co0, ro = ro0;
        #pragma unroll 1
        for (int it = 0; it < IW; ++it) {
            if (gb0 + (unsigned)(it * 64) >= (unsigned)n) break;
            float4 a0 = *reinterpret_cast<const float4*>(ap);
            float4 a1 = *reinterpret_cast<const float4*>(ap + 4);
            f32x4  cv = *reinterpret_cast<const f32x4*>(c + co);
            COMPUTE(a0, a1, cv, co, ro);
            ap += astride; co += 1024u; ro += 64u;
        }
    }
#undef COMPUTE
}

extern "C" void kernel_launch(void* const* d_in, const int* in_sizes, int n_in,
                              void* d_out, int out_size, void* d_ws, size_t ws_size,
                              hipStream_t stream) {
    const float* x       = (const float*)d_in[0];
    // d_in[1] = edge_index (int64, unused), d_in[2] = edge_attr (unused)
    const float* h       = (const float*)d_in[3];
    const float* c       = (const float*)d_in[4];
    const float* Wx      = (const float*)d_in[5];
    const float* bx      = (const float*)d_in[6];
    const float* Wh      = (const float*)d_in[7];
    const float* bh      = (const float*)d_in[8];
    const float* w_peep  = (const float*)d_in[9];
    const float* b_gates = (const float*)d_in[10];
    const float* W_lin   = (const float*)d_in[11];
    const float* b_lin   = (const float*)d_in[12];
    float* out = (float*)d_out;

    const int n = in_sizes[0] / 8;  // N = 1,000,000
    const int blocks = (n + NPB - 1) / NPB;
    lstm_mfma_kernel<<<blocks, 256, 0, stream>>>(
        x, h, c, Wx, bx, Wh, bh, w_peep, b_gates, W_lin, b_lin, out, n);
}

// Round 11
// 51.130 us; speedup vs baseline: 2.0704x; 2.0704x over previous
//
#include <hip/hip_runtime.h>
#include <hip/hip_bf16.h>
#include <math.h>

// GConvLSTM cell via MFMA (graph inputs are dead code in the reference).
// Transposed gate GEMM (R7 layout): g^T = W^T @ [x|h|1]^T via
// mfma_f32_16x16x32_bf16(A=W-frag, B=X-frag); lane (q=lane&15, kb=lane>>4)
// owns node gb0+q, dims kb*4..kb*4+3 of every gate -> all c/h_new/c_new
// accesses are wave-contiguous float4; out-reduce = in-lane 4-dot + 2 shfl.
// Bias through the MFMA (R10-proven correct): W row 24 = bx+bh+b_gates (bf16),
// kb==3 lanes' X-frag = {1,0,...}; accumulators init from inline 0 -> frees
// the 16 bias VGPRs.
// R11 vs R10: NO forced launch bound. R10's (256,8) made the allocator spill
// ~30 regs to scratch (VGPR 32, +166MB scratch traffic, 105us) even though
// occupancy doubled to 64% as predicted. Natural allocation should land ~60
// VGPR (R9's 76 minus 16 bias) -> <=64 -> 8 blocks/CU without spills.
// Keeps: 2-deep pipeline (R9), nontemporal h_new/c_new stores (R8).
// d_out layout: [N] out | [N*16] h_new | [N*16] c_new.  Requires n % 16 == 0.

typedef short bf16x8 __attribute__((ext_vector_type(8)));
typedef float f32x4 __attribute__((ext_vector_type(4)));

#define LOG2E 1.44269504088896f

__device__ __forceinline__ float sig1(float v) {
    return __builtin_amdgcn_rcpf(1.0f + __builtin_amdgcn_exp2f(-LOG2E * v));
}
__device__ __forceinline__ float tanh1(float v) {
    return 1.0f - 2.0f * __builtin_amdgcn_rcpf(__builtin_amdgcn_exp2f((2.0f * LOG2E) * v) + 1.0f);
}
__device__ __forceinline__ f32x4 sig4(f32x4 v) {
    f32x4 r; r[0]=sig1(v[0]); r[1]=sig1(v[1]); r[2]=sig1(v[2]); r[3]=sig1(v[3]); return r;
}
__device__ __forceinline__ f32x4 tanh4(f32x4 v) {
    f32x4 r; r[0]=tanh1(v[0]); r[1]=tanh1(v[1]); r[2]=tanh1(v[2]); r[3]=tanh1(v[3]); return r;
}
__device__ __forceinline__ short f2bf(float f) {
    __bf16 b = (__bf16)f;          // pairs fuse to v_cvt_pk_bf16_f32
    short s; __builtin_memcpy(&s, &b, 2); return s;
}
__device__ __forceinline__ f32x4 max4z(f32x4 a) {
    f32x4 r; r[0]=fmaxf(a[0],0.f); r[1]=fmaxf(a[1],0.f); r[2]=fmaxf(a[2],0.f); r[3]=fmaxf(a[3],0.f); return r;
}

#define IW 8                       // 64-node tiles per block (even!)
#define NPB (64 * IW)              // 512 nodes per block

__global__ __launch_bounds__(256) void lstm_mfma_kernel(
    const float* __restrict__ x,       // N x 8
    const float* __restrict__ h,       // N x 16
    const float* __restrict__ c,       // N x 16
    const float* __restrict__ Wx,      // 8 x 64
    const float* __restrict__ bx,      // 64
    const float* __restrict__ Wh,      // 16 x 64
    const float* __restrict__ bh,      // 64
    const float* __restrict__ w_peep,  // 3 x 16
    const float* __restrict__ b_gates, // 4 x 16
    const float* __restrict__ W_lin,   // 16
    const float* __restrict__ b_lin,   // 1
    float* __restrict__ dout,
    int n)
{
    const int lane = threadIdx.x & 63;
    const int wave = threadIdx.x >> 6;
    const int q  = lane & 15;   // A-role: dim; B/D-role: node offset
    const int kb = lane >> 4;   // k-block (8 k's each); D-role: dim block
    const bool kb3 = (kb == 3);

    // ---- weight A-fragment: wfrag[t][e] = W[kb*8+e][t*16+q]
    // W = [Wx(8) ; Wh(16) ; bias-row(1) ; 0pad(7)], bias row = bx+bh+b_gates.
    // kb==3 X-frag is the constant {1,0,...}: bias*1 lands in the accumulator,
    // rows 25..31 are zero.
    bf16x8 wfrag[4];
    #pragma unroll
    for (int t = 0; t < 4; ++t) {
        #pragma unroll
        for (int e = 0; e < 8; ++e) {
            const int r = kb * 8 + e;
            float w = 0.0f;
            if (r < 8)        w = Wx[r * 64 + t * 16 + q];
            else if (r < 24)  w = Wh[(r - 8) * 64 + t * 16 + q];
            else if (r == 24) w = bx[t * 16 + q] + bh[t * 16 + q] + b_gates[t * 16 + q];
            wfrag[t][e] = f2bf(w);
        }
    }

    // ---- per-lane epilogue constants for dims dd..dd+3
    const int dd = kb * 4;
    f32x4 pp0, pp1, pp2, wl4;
    #pragma unroll
    for (int e = 0; e < 4; ++e) {
        pp0[e] = w_peep[dd + e]; pp1[e] = w_peep[16 + dd + e]; pp2[e] = w_peep[32 + dd + e];
        wl4[e] = W_lin[dd + e];
    }
    const float bl = b_lin[0];

    const unsigned blockBase = (unsigned)blockIdx.x * NPB;
    const unsigned gb0   = blockBase + (unsigned)wave * 16u;  // wave's first node
    const unsigned node0 = gb0 + (unsigned)q;

    // per-lane X pointer (B-frag): x rows for kb==0, h rows otherwise
    // (kb==3 loads are discarded: xf is overwritten with {1,0,...})
    const float* aptr;
    unsigned astride;
    if (kb == 0) { aptr = x + (size_t)node0 * 8;                        astride = 64u * 8;  }
    else         { aptr = h + (size_t)node0 * 16 + ((kb == 2) ? 8 : 0); astride = 64u * 16; }

    const unsigned co0 = node0 * 16u + (unsigned)dd;  // c / h_new / c_new float4 offset
    const unsigned ro0 = node0;                       // out offset (kb==0 lanes store)
    float* hob = dout + (size_t)n;        // h_new base
    float* cob = dout + (size_t)n * 17;   // c_new base

    // compute one iteration from registers A0,A1,CV; stores at CO/RO
#define COMPUTE(A0, A1, CV, CO, RO)                                            \
    {                                                                          \
        bf16x8 xf;                                                             \
        xf[0] = f2bf((A0).x); xf[1] = f2bf((A0).y);                            \
        xf[2] = f2bf((A0).z); xf[3] = f2bf((A0).w);                            \
        xf[4] = f2bf((A1).x); xf[5] = f2bf((A1).y);                            \
        xf[6] = f2bf((A1).z); xf[7] = f2bf((A1).w);                            \
        if (kb3) {                                                             \
            xf[0] = (short)0x3F80; xf[1] = 0; xf[2] = 0; xf[3] = 0;            \
            xf[4] = 0; xf[5] = 0; xf[6] = 0; xf[7] = 0;                        \
        }                                                                      \
        f32x4 accI = {0.f, 0.f, 0.f, 0.f};                                     \
        f32x4 accF = {0.f, 0.f, 0.f, 0.f};                                     \
        f32x4 accC = {0.f, 0.f, 0.f, 0.f};                                     \
        f32x4 accO = {0.f, 0.f, 0.f, 0.f};                                     \
        accI = __builtin_amdgcn_mfma_f32_16x16x32_bf16(wfrag[0], xf, accI, 0, 0, 0); \
        accF = __builtin_amdgcn_mfma_f32_16x16x32_bf16(wfrag[1], xf, accF, 0, 0, 0); \
        accC = __builtin_amdgcn_mfma_f32_16x16x32_bf16(wfrag[2], xf, accC, 0, 0, 0); \
        accO = __builtin_amdgcn_mfma_f32_16x16x32_bf16(wfrag[3], xf, accO, 0, 0, 0); \
        f32x4 iv = sig4(pp0 * (CV) + accI);                                    \
        f32x4 fv = sig4(pp1 * (CV) + accF);                                    \
        f32x4 tv = tanh4(accC);                                                \
        f32x4 cn = fv * (CV) + iv * tv;                                        \
        f32x4 ov = sig4(pp2 * cn + accO);                                      \
        f32x4 hn = ov * tanh4(cn);                                             \
        __builtin_nontemporal_store(hn, reinterpret_cast<f32x4*>(hob + (CO))); \
        __builtin_nontemporal_store(cn, reinterpret_cast<f32x4*>(cob + (CO))); \
        f32x4 rr = max4z(hn) * wl4;                                            \
        float os = (rr[0] + rr[1]) + (rr[2] + rr[3]);                          \
        os += __shfl_xor(os, 16);                                              \
        os += __shfl_xor(os, 32);                                              \
        if (kb == 0) dout[RO] = os + bl;                                       \
    }

    if (blockBase + NPB <= (unsigned)n) {
        // full block: 2-deep pipeline with two named register sets.
        // A = even iterations (0,2,4,6), B = odd iterations (1,3,5,7).
        const float* apA = aptr;
        const float* apB = aptr + astride;
        unsigned coA = co0,        coB = co0 + 1024u;
        unsigned roA = ro0,        roB = ro0 + 64u;
        const unsigned astep = 2u * astride;

        float4 a0A = *reinterpret_cast<const float4*>(apA);
        float4 a1A = *reinterpret_cast<const float4*>(apA + 4);
        f32x4  cvA = *reinterpret_cast<const f32x4*>(c + coA);
        float4 a0B = *reinterpret_cast<const float4*>(apB);
        float4 a1B = *reinterpret_cast<const float4*>(apB + 4);
        f32x4  cvB = *reinterpret_cast<const f32x4*>(c + coB);

        #pragma unroll 1
        for (int k = 0; k < (IW - 2) / 2; ++k) {
            // prefetch iter 2k+2 (next A), then compute iter 2k (A)
            const float* npA = apA + astep;
            float4 t0 = *reinterpret_cast<const float4*>(npA);
            float4 t1 = *reinterpret_cast<const float4*>(npA + 4);
            f32x4  tc = *reinterpret_cast<const f32x4*>(c + coA + 2048u);
            COMPUTE(a0A, a1A, cvA, coA, roA);
            a0A = t0; a1A = t1; cvA = tc;
            apA = npA; coA += 2048u; roA += 128u;

            // prefetch iter 2k+3 (next B), then compute iter 2k+1 (B)
            const float* npB = apB + astep;
            float4 u0 = *reinterpret_cast<const float4*>(npB);
            float4 u1 = *reinterpret_cast<const float4*>(npB + 4);
            f32x4  uc = *reinterpret_cast<const f32x4*>(c + coB + 2048u);
            COMPUTE(a0B, a1B, cvB, coB, roB);
            a0B = u0; a1B = u1; cvB = uc;
            apB = npB; coB += 2048u; roB += 128u;
        }
        COMPUTE(a0A, a1A, cvA, coA, roA);   // iter IW-2
        COMPUTE(a0B, a1B, cvB, coB, roB);   // iter IW-1
    } else {
        // tail block (at most one): group-granular bounds check (n % 16 == 0)
        const float* ap = aptr;
        unsigned co = co0, ro = ro0;
        #pragma unroll 1
        for (int it = 0; it < IW; ++it) {
            if (gb0 + (unsigned)(it * 64) >= (unsigned)n) break;
            float4 a0 = *reinterpret_cast<const float4*>(ap);
            float4 a1 = *reinterpret_cast<const float4*>(ap + 4);
            f32x4  cv = *reinterpret_cast<const f32x4*>(c + co);
            COMPUTE(a0, a1, cv, co, ro);
            ap += astride; co += 1024u; ro += 64u;
        }
    }
#undef COMPUTE
}

extern "C" void kernel_launch(void* const* d_in, const int* in_sizes, int n_in,
                              void* d_out, int out_size, void* d_ws, size_t ws_size,
                              hipStream_t stream) {
    const float* x       = (const float*)d_in[0];
    // d_in[1] = edge_index (int64, unused), d_in[2] = edge_attr (unused)
    const float* h       = (const float*)d_in[3];
    const float* c       = (const float*)d_in[4];
    const float* Wx      = (const float*)d_in[5];
    const float* bx      = (const float*)d_in[6];
    const float* Wh      = (const float*)d_in[7];
    const float* bh      = (const float*)d_in[8];
    const float* w_peep  = (const float*)d_in[9];
    const float* b_gates = (const float*)d_in[10];
    const float* W_lin   = (const float*)d_in[11];
    const float* b_lin   = (const float*)d_in[12];
    float* out = (float*)d_out;

    const int n = in_sizes[0] / 8;  // N = 1,000,000
    const int blocks = (n + NPB - 1) / NPB;
    lstm_mfma_kernel<<<blocks, 256, 0, stream>>>(
        x, h, c, Wx, bx, Wh, bh, w_peep, b_gates, W_lin, b_lin, out, n);
}